// Round 1
// baseline (4733.006 us; speedup 1.0000x reference)
//
#include <hip/hip_runtime.h>
#include <stdint.h>

#define GLOBAL_AS __attribute__((address_space(1)))
#define LDS_AS    __attribute__((address_space(3)))

typedef _Float16 f16;
typedef _Float16 half8 __attribute__((ext_vector_type(8)));
typedef float    f32x4 __attribute__((ext_vector_type(4)));

constexpr int B_  = 16;
constexpr int T_  = 2048;
constexpr int IN_ = 65;
constexpr int HID = 64;
constexpr int G4  = 256;      // 4*HID
constexpr int FW  = 72;       // padded frame width (25*72 = 1800)
constexpr int KP  = 1824;     // padded K for layer0 (57*32)
constexpr int KC0 = KP / 32;  // 57

// ---- workspace layout (bytes) ----
constexpr size_t OFF_XF   = 0;                          // [B][T][FW] f16
constexpr size_t SZ_XF    = (size_t)B_ * T_ * FW * 2;   // 4,718,592
constexpr size_t OFF_WP0  = OFF_XF + SZ_XF;             // [KC0][16][64][8] f16
constexpr size_t SZ_WP0   = (size_t)KC0 * 16 * 64 * 8 * 2;
constexpr size_t OFF_WHHF = OFF_WP0 + SZ_WP0;           // 3 x [16][2][64][8] f16
constexpr size_t SZ_WHHF1 = (size_t)16 * 2 * 64 * 8 * 2;
constexpr size_t OFF_WIHF = OFF_WHHF + 3 * SZ_WHHF1;    // 2 x [2][16][64][8] f16
constexpr size_t SZ_WIHF1 = (size_t)2 * 16 * 64 * 8 * 2;
constexpr size_t OFF_BC   = OFF_WIHF + 2 * SZ_WIHF1;    // 3 x [256] f32
constexpr size_t OFF_PRE  = ((OFF_BC + 3 * 256 * 4 + 1023) / 1024) * 1024;  // [T][B][256] f32 (permuted+swizzled)
constexpr size_t SZ_PRE   = (size_t)T_ * B_ * G4 * 4;   // 33,554,432
constexpr size_t OFF_H0   = OFF_PRE + SZ_PRE;           // [B][T][HID] f16
constexpr size_t SZ_H     = (size_t)B_ * T_ * HID * 2;  // 4,194,304
constexpr size_t OFF_H1   = OFF_H0 + SZ_H;
constexpr size_t OFF_H2   = OFF_H1 + SZ_H;

__device__ __forceinline__ void async_copy16(const void* g, void* l) {
  __builtin_amdgcn_global_load_lds((const GLOBAL_AS void*)g, (LDS_AS void*)l, 16, 0, 0);
}

// within-row byte offset for pre[t][b][g]: permute g=(q*64+j) -> (j*16|q*4), XOR-swizzle by batch
__device__ __forceinline__ int pre_col_byte(int b, int g) {
  int j = g & 63, q = g >> 6;
  return ((j << 4) | (q << 2)) ^ ((b & 7) << 4);
}

__device__ __forceinline__ float fsig(float x) {
  return __builtin_amdgcn_rcpf(1.f + __builtin_amdgcn_exp2f(-1.4426950408889634f * x));
}
__device__ __forceinline__ float ftanh(float x) {
  return 1.f - 2.f * __builtin_amdgcn_rcpf(1.f + __builtin_amdgcn_exp2f(2.8853900817779268f * x));
}

// ================= pack kernel =================
__global__ void pack_kernel(const float* __restrict__ in0, const float* __restrict__ Wih0,
                            const float* __restrict__ Whh0, const float* __restrict__ bih0, const float* __restrict__ bhh0,
                            const float* __restrict__ Wih1, const float* __restrict__ Whh1, const float* __restrict__ bih1, const float* __restrict__ bhh1,
                            const float* __restrict__ Wih2, const float* __restrict__ Whh2, const float* __restrict__ bih2, const float* __restrict__ bhh2,
                            f16* __restrict__ xf, f16* __restrict__ wp0,
                            f16* __restrict__ whhf, f16* __restrict__ wihf, float* __restrict__ bc)
{
  const int stride = gridDim.x * blockDim.x;
  const int tid0 = blockIdx.x * blockDim.x + threadIdx.x;

  // xf: [B][T][FW], zero-pad f >= 65
  const int NX = B_ * T_ * FW;
  for (int i = tid0; i < NX; i += stride) {
    int f = i % FW; int bt = i / FW;
    float v = (f < IN_) ? in0[(size_t)bt * IN_ + f] : 0.f;
    xf[i] = (f16)v;
  }
  // wp0: [kc][nt][lane][8] ; k' = kc*32 + (l>>4)*8 + j ; g = nt*16 + (l&15)
  const int NW0 = KC0 * 16 * 64 * 8;
  for (int i = tid0; i < NW0; i += stride) {
    int j = i & 7, l = (i >> 3) & 63, nt = (i >> 9) & 15, kc = i >> 13;
    int kp = kc * 32 + ((l >> 4) * 8 + j);
    int g  = nt * 16 + (l & 15);
    int d = kp / FW, f = kp % FW;
    float v = (kp < 1800 && f < IN_) ? Wih0[(size_t)g * 1625 + d * IN_ + f] : 0.f;
    wp0[i] = (f16)v;
  }
  // whhf: per layer [nt][kf][lane][8]: B[k][n] = Whh[n][k]
  const float* whhs[3] = {Whh0, Whh1, Whh2};
  for (int i = tid0; i < 3 * 16384; i += stride) {
    int L = i >> 14, r = i & 16383;
    int j = r & 7, l = (r >> 3) & 63, kf = (r >> 9) & 1, nt = r >> 10;
    int k = kf * 32 + ((l >> 4) * 8 + j);
    int g = nt * 16 + (l & 15);
    whhf[i] = (f16)whhs[L][g * 64 + k];
  }
  // wihf: per layer [kc][nt][lane][8]: B[k][n] = Wih[n][k], K=64
  const float* wihs[2] = {Wih1, Wih2};
  for (int i = tid0; i < 2 * 16384; i += stride) {
    int L = i >> 14, r = i & 16383;
    int j = r & 7, l = (r >> 3) & 63, nt = (r >> 9) & 15, kc = r >> 13;
    int k = kc * 32 + ((l >> 4) * 8 + j);
    int g = nt * 16 + (l & 15);
    wihf[i] = (f16)wihs[L][g * 64 + k];
  }
  // combined biases
  const float* bis[3] = {bih0, bih1, bih2};
  const float* bhs[3] = {bhh0, bhh1, bhh2};
  for (int i = tid0; i < 3 * 256; i += stride) {
    int L = i >> 8, g = i & 255;
    bc[i] = bis[L][g] + bhs[L][g];
  }
}

// ================= layer-0 windowed GEMM =================
// grid (32, 16): x = t-tile (64 rows), y = batch. 256 threads = 4 waves.
__global__ __launch_bounds__(256) void gemm0_kernel(const f16* __restrict__ xf, const f16* __restrict__ wp0,
                                                    const float* __restrict__ bc0, float* __restrict__ pre)
{
  __shared__ __align__(16) f16 frames[90 * FW];   // 12,960 B
  __shared__ __align__(16) f16 bbuf[16 * 64 * 8]; // 16,384 B
  const int tid = threadIdx.x, l = tid & 63, w = tid >> 6;
  const int b = blockIdx.y, t0 = blockIdx.x * 64;

  // zero frames (covers t-edge padding and the k'>=1800 tail rows)
  for (int c = tid; c < 810; c += 256) *(f32x4*)(&frames[c * 8]) = (f32x4)0.f;
  __syncthreads();

  // stage valid frame range [s0, s1) of this batch
  {
    const int st = t0 - 12;
    const int s0 = st < 0 ? 0 : st;
    const int s1 = (t0 + 78) < T_ ? (t0 + 78) : T_;
    const int dstrow = s0 - st;
    const int nchunk = (s1 - s0) * 9;  // 16B chunks (144 B/row)
    const f16* gsrc = xf + ((size_t)b * T_ + s0) * FW;
    for (int base = 0; base < 810; base += 256) {
      int idx = base + w * 64 + l;
      if (idx < nchunk) {
        char* ldsb = (char*)frames + dstrow * 144 + (base + w * 64) * 16;
        async_copy16((const char*)gsrc + (size_t)(base + w * 64) * 16 + l * 16, ldsb);
      }
    }
  }

  f32x4 acc[16];
#pragma unroll
  for (int i = 0; i < 16; ++i) acc[i] = (f32x4)0.f;

  for (int kc = 0; kc < KC0; ++kc) {
    __syncthreads();  // drains previous loads/reads; protects bbuf
    const f16* wsrc = wp0 + (size_t)kc * 8192;
#pragma unroll
    for (int i = 0; i < 4; ++i) {
      char* ldsb = (char*)bbuf + (i * 256 + w * 64) * 16;
      async_copy16((const char*)wsrc + (size_t)(i * 256 + w * 64 + l) * 16, ldsb);
    }
    __syncthreads();  // vmcnt(0) drain -> bbuf ready

    int kp0 = kc * 32 + ((l >> 4) * 8);
    int d = kp0 / FW, f = kp0 % FW;
    int r = w * 16 + (l & 15);
    half8 af = *(const half8*)(&frames[(r + d) * FW + f]);
#pragma unroll
    for (int nt = 0; nt < 16; ++nt) {
      half8 bf = *(const half8*)(&bbuf[(nt * 64 + l) * 8]);
      acc[nt] = __builtin_amdgcn_mfma_f32_16x16x32_f16(af, bf, acc[nt], 0, 0, 0);
    }
  }

  // epilogue: bias + permuted/swizzled store into pre[t][b][...]
  const int n_ = l & 15, grp = l >> 4;
#pragma unroll
  for (int nt = 0; nt < 16; ++nt) {
    int g = nt * 16 + n_;
    float bias = bc0[g];
    int colByte = pre_col_byte(b, g);
#pragma unroll
    for (int rr = 0; rr < 4; ++rr) {
      int t = t0 + w * 16 + grp * 4 + rr;
      *(float*)((char*)pre + (size_t)t * 16384 + (size_t)b * 1024 + colByte) = acc[nt][rr] + bias;
    }
  }
}

// ================= inter-layer GEMM (pre = h_prev @ WihT + bias) =================
// grid (32, 16), 512 threads = 8 waves: wave = (ms = w&3 [M-subtile], nh = w>>2 [N-half])
__global__ __launch_bounds__(512) void g_kernel(const f16* __restrict__ hprev, const f16* __restrict__ wpf,
                                                const float* __restrict__ bcL, float* __restrict__ pre)
{
  __shared__ __align__(16) f16 albuf[64 * 64];  // 8 KB, XOR-swizzled rows
  const int tid = threadIdx.x, l = tid & 63, w = tid >> 6;
  const int b = blockIdx.y, t0 = blockIdx.x * 64;
  const int ms = w & 3, nh = w >> 2;

  // reg-stage A with swizzled ds_write (16B per thread)
  {
    const char* src = (const char*)(hprev + ((size_t)b * T_ + t0) * HID);
    f32x4 v = *(const f32x4*)(src + (size_t)tid * 16);
    int r = tid >> 3, s = tid & 7;
    *(f32x4*)((char*)albuf + r * 128 + ((s * 16) ^ ((r & 7) << 4))) = v;
  }
  __syncthreads();

  // B fragments direct global->VGPR
  half8 bf[8][2];
#pragma unroll
  for (int i = 0; i < 8; ++i) {
    int nt = nh * 8 + i;
#pragma unroll
    for (int kc = 0; kc < 2; ++kc)
      bf[i][kc] = *(const half8*)(wpf + (((size_t)kc * 16 + nt) * 64 + l) * 8);
  }
  // A fragments (swizzled read)
  half8 af[2];
#pragma unroll
  for (int kc = 0; kc < 2; ++kc) {
    int r = ms * 16 + (l & 15);
    int kbyte = kc * 64 + ((l >> 4) * 16);
    af[kc] = *(const half8*)((const char*)albuf + r * 128 + (kbyte ^ ((r & 7) << 4)));
  }

  f32x4 acc[8];
#pragma unroll
  for (int i = 0; i < 8; ++i) {
    acc[i] = __builtin_amdgcn_mfma_f32_16x16x32_f16(af[0], bf[i][0], (f32x4)0.f, 0, 0, 0);
    acc[i] = __builtin_amdgcn_mfma_f32_16x16x32_f16(af[1], bf[i][1], acc[i], 0, 0, 0);
  }

  const int n_ = l & 15, grp = l >> 4;
#pragma unroll
  for (int i = 0; i < 8; ++i) {
    int g = (nh * 8 + i) * 16 + n_;
    float bias = bcL[g];
    int colByte = pre_col_byte(b, g);
#pragma unroll
    for (int rr = 0; rr < 4; ++rr) {
      int t = t0 + ms * 16 + grp * 4 + rr;
      *(float*)((char*)pre + (size_t)t * 16384 + (size_t)b * 1024 + colByte) = acc[i][rr] + bias;
    }
  }
}

// ================= LSTM recurrence (one layer, all 16 batches, 1 block) =================
// 256 threads = 4 waves. Wave w owns N-tiles {w, 4+w, 8+w, 12+w} -> lane has i,f,g,o
// for its (b, j=16w+n) pairs entirely in-register.
__global__ __launch_bounds__(256) void r_kernel(const float* __restrict__ pre, const f16* __restrict__ whhf,
                                                f16* __restrict__ hout)
{
  __shared__ __align__(16) char lds[4 * 16384 + 2 * 2048];  // 68 KB: pre ring + H ping-pong
  char* ring = lds;
  char* Hb   = lds + 65536;
  const int tid = threadIdx.x, l = tid & 63, w = tid >> 6;
  const int n_ = l & 15, grp = l >> 4;
  const int j = w * 16 + n_;

  // recurrent weight fragments (held in VGPRs the whole kernel)
  half8 bf[4][2];
#pragma unroll
  for (int u = 0; u < 4; ++u) {
    int nt = u * 4 + w;
#pragma unroll
    for (int kf = 0; kf < 2; ++kf)
      bf[u][kf] = *(const half8*)(whhf + (((size_t)nt * 2 + kf) * 64 + l) * 8);
  }

  // zero H[0]
  if (tid < 128) *(f32x4*)(Hb + tid * 16) = (f32x4)0.f;
  float c0 = 0.f, c1 = 0.f, c2 = 0.f, c3 = 0.f;

  // prologue: prefetch pre slots 0..2 (4 x 16B per wave per slot)
#pragma unroll
  for (int s = 0; s < 3; ++s) {
    const char* gs = (const char*)pre + (size_t)s * 16384 + w * 4096;
    char* lb = ring + s * 16384 + w * 4096;
#pragma unroll
    for (int i = 0; i < 4; ++i)
      async_copy16(gs + i * 1024 + l * 16, lb + i * 1024);
  }

  int cur = 0;
  for (int t = 0; t < T_; ++t) {
    // sync 1: H[cur] ready (cross-wave)
    asm volatile("s_waitcnt lgkmcnt(0)" ::: "memory");
    __builtin_amdgcn_s_barrier();
    __builtin_amdgcn_sched_barrier(0);

    // MFMA phase: G = H[cur] @ WhhT
    char* Hc = Hb + cur * 2048;
    half8 af[2];
#pragma unroll
    for (int kf = 0; kf < 2; ++kf) {
      int bb = l & 15;
      int kbyte = kf * 64 + ((l >> 4) * 16);
      af[kf] = *(const half8*)(Hc + bb * 128 + (kbyte ^ ((bb & 7) << 4)));
    }
    f32x4 acc[4];
#pragma unroll
    for (int u = 0; u < 4; ++u) {
      acc[u] = __builtin_amdgcn_mfma_f32_16x16x32_f16(af[0], bf[u][0], (f32x4)0.f, 0, 0, 0);
      acc[u] = __builtin_amdgcn_mfma_f32_16x16x32_f16(af[1], bf[u][1], acc[u], 0, 0, 0);
    }

    // sync 2: pre slot t staged (counted vmcnt: 8 VMEM ops issued per step, slot-t
    // prefetch was issued at step t-3 -> vmcnt(16) drains it; warmup uses 0)
    if (t < 2) { asm volatile("s_waitcnt vmcnt(0)" ::: "memory"); }
    else       { asm volatile("s_waitcnt vmcnt(16)" ::: "memory"); }
    __builtin_amdgcn_s_barrier();
    __builtin_amdgcn_sched_barrier(0);

    const char* slot = ring + (t & 3) * 16384;
    char* Hn = Hb + (cur ^ 1) * 2048;
    float* cs[4] = {&c0, &c1, &c2, &c3};
#pragma unroll
    for (int r = 0; r < 4; ++r) {
      int bb = grp * 4 + r;
      f32x4 p = *(const f32x4*)(slot + bb * 1024 + ((j << 4) ^ ((bb & 7) << 4)));
      float iv = acc[0][r] + p.x;
      float fv = acc[1][r] + p.y;
      float gv = acc[2][r] + p.z;
      float ov = acc[3][r] + p.w;
      float cc = fsig(fv) * (*cs[r]) + fsig(iv) * ftanh(gv);
      *cs[r] = cc;
      float hv = fsig(ov) * ftanh(cc);
      f16 h16 = (f16)hv;
      *(f16*)(Hn + bb * 128 + ((j * 2) ^ ((bb & 7) << 4))) = h16;
      hout[((size_t)bb * T_ + t) * HID + j] = h16;
    }

    // prefetch slot t+3 (dummy re-read of slot-0 data at the tail keeps the
    // 8-VMEM-ops-per-step accounting uniform; the dummy's dest slot is never read)
    {
      int tp = (t + 3 < T_) ? (t + 3) : 0;
      const char* gs = (const char*)pre + (size_t)tp * 16384 + w * 4096;
      char* lb = ring + ((t + 3) & 3) * 16384 + w * 4096;
#pragma unroll
      for (int i = 0; i < 4; ++i)
        async_copy16(gs + i * 1024 + l * 16, lb + i * 1024);
    }
    cur ^= 1;
  }
}

// ================= final projection =================
__global__ __launch_bounds__(256) void fin_kernel(const f16* __restrict__ h2, const float* __restrict__ Wout,
                                                  const float* __restrict__ bout, float* __restrict__ out)
{
  __shared__ float wl[64];
  const int tid = threadIdx.x;
  if (tid < 64) wl[tid] = Wout[tid];
  __syncthreads();
  const int idx = blockIdx.x * 256 + tid;  // = b*T + t
  const f16* hr = h2 + (size_t)idx * HID;
  float acc = bout[0];
#pragma unroll
  for (int i = 0; i < 64; i += 8) {
    half8 hv = *(const half8*)(hr + i);
#pragma unroll
    for (int k = 0; k < 8; ++k) {
      float h = (float)hv[k];
      h = fmaxf(h, 0.f);
      acc += h * wl[i + k];
    }
  }
  out[idx] = fsig(acc);
}

// ================= launcher =================
extern "C" void kernel_launch(void* const* d_in, const int* in_sizes, int n_in,
                              void* d_out, int out_size, void* d_ws, size_t ws_size,
                              hipStream_t stream)
{
  (void)in_sizes; (void)n_in; (void)out_size; (void)ws_size;
  const float* in0  = (const float*)d_in[0];
  const float* Wih0 = (const float*)d_in[1];
  const float* Whh0 = (const float*)d_in[2];
  const float* bih0 = (const float*)d_in[3];
  const float* bhh0 = (const float*)d_in[4];
  const float* Wih1 = (const float*)d_in[5];
  const float* Whh1 = (const float*)d_in[6];
  const float* bih1 = (const float*)d_in[7];
  const float* bhh1 = (const float*)d_in[8];
  const float* Wih2 = (const float*)d_in[9];
  const float* Whh2 = (const float*)d_in[10];
  const float* bih2 = (const float*)d_in[11];
  const float* bhh2 = (const float*)d_in[12];
  const float* Wout = (const float*)d_in[13];
  const float* bout = (const float*)d_in[14];
  float* out = (float*)d_out;

  char* ws = (char*)d_ws;
  f16*   xf   = (f16*)(ws + OFF_XF);
  f16*   wp0  = (f16*)(ws + OFF_WP0);
  f16*   whhf = (f16*)(ws + OFF_WHHF);
  f16*   wihf = (f16*)(ws + OFF_WIHF);
  float* bc   = (float*)(ws + OFF_BC);
  float* pre  = (float*)(ws + OFF_PRE);
  f16*   h0   = (f16*)(ws + OFF_H0);
  f16*   h1   = (f16*)(ws + OFF_H1);
  f16*   h2   = (f16*)(ws + OFF_H2);

  pack_kernel<<<256, 256, 0, stream>>>(in0, Wih0, Whh0, bih0, bhh0,
                                       Wih1, Whh1, bih1, bhh1,
                                       Wih2, Whh2, bih2, bhh2,
                                       xf, wp0, whhf, wihf, bc);
  gemm0_kernel<<<dim3(32, 16), 256, 0, stream>>>(xf, wp0, bc, pre);
  r_kernel<<<1, 256, 0, stream>>>(pre, whhf, h0);
  g_kernel<<<dim3(32, 16), 512, 0, stream>>>(h0, wihf, bc + 256, pre);
  r_kernel<<<1, 256, 0, stream>>>(pre, whhf + 16384, h1);
  g_kernel<<<dim3(32, 16), 512, 0, stream>>>(h1, wihf + 16384, bc + 512, pre);
  r_kernel<<<1, 256, 0, stream>>>(pre, whhf + 32768, h2);
  fin_kernel<<<128, 256, 0, stream>>>(h2, Wout, bout, out);
}

// Round 2
// 2582.446 us; speedup vs baseline: 1.8328x; 1.8328x over previous
//
#include <hip/hip_runtime.h>
#include <stdint.h>

#define GLOBAL_AS __attribute__((address_space(1)))
#define LDS_AS    __attribute__((address_space(3)))

typedef _Float16 f16;
typedef _Float16 half8 __attribute__((ext_vector_type(8)));
typedef float    f32x4 __attribute__((ext_vector_type(4)));

constexpr int B_  = 16;
constexpr int T_  = 2048;
constexpr int IN_ = 65;
constexpr int HID = 64;
constexpr int G4  = 256;      // 4*HID
constexpr int FW  = 72;       // padded frame width (25*72 = 1800)
constexpr int KP  = 1824;     // padded K for layer0 (57*32)
constexpr int KC0 = KP / 32;  // 57

// ---- workspace layout (bytes) ----
constexpr size_t OFF_XF   = 0;                          // [B][T][FW] f16
constexpr size_t SZ_XF    = (size_t)B_ * T_ * FW * 2;   // 4,718,592
constexpr size_t OFF_WP0  = OFF_XF + SZ_XF;             // [KC0][16][64][8] f16
constexpr size_t SZ_WP0   = (size_t)KC0 * 16 * 64 * 8 * 2;
constexpr size_t OFF_WHHF = OFF_WP0 + SZ_WP0;           // 3 x [w*4+u][kf][64][8] f16
constexpr size_t SZ_WHHF1 = (size_t)16 * 2 * 64 * 8 * 2;
constexpr size_t OFF_WIHF = OFF_WHHF + 3 * SZ_WHHF1;    // 2 x [2][16][64][8] f16
constexpr size_t SZ_WIHF1 = (size_t)2 * 16 * 64 * 8 * 2;
constexpr size_t OFF_BC   = OFF_WIHF + 2 * SZ_WIHF1;    // 3 x [256] f32
constexpr size_t OFF_PRE  = ((OFF_BC + 3 * 256 * 4 + 1023) / 1024) * 1024;  // [T][B][256] f32 (permuted+swizzled)
constexpr size_t SZ_PRE   = (size_t)T_ * B_ * G4 * 4;   // 33,554,432
constexpr size_t OFF_H0   = OFF_PRE + SZ_PRE;           // [B][T][HID] f16
constexpr size_t SZ_H     = (size_t)B_ * T_ * HID * 2;  // 4,194,304
constexpr size_t OFF_H1   = OFF_H0 + SZ_H;
constexpr size_t OFF_H2   = OFF_H1 + SZ_H;

__device__ __forceinline__ void async_copy16(const void* g, void* l) {
  __builtin_amdgcn_global_load_lds((const GLOBAL_AS void*)g, (LDS_AS void*)l, 16, 0, 0);
}

// within-row byte offset for pre[t][b][g]: permute g=(q*64+j) -> (j*16|q*4), XOR-swizzle by batch
__device__ __forceinline__ int pre_col_byte(int b, int g) {
  int j = g & 63, q = g >> 6;
  return ((j << 4) | (q << 2)) ^ ((b & 7) << 4);
}

__device__ __forceinline__ float fsig(float x) {
  return __builtin_amdgcn_rcpf(1.f + __builtin_amdgcn_exp2f(-1.4426950408889634f * x));
}
__device__ __forceinline__ float ftanh(float x) {
  return 1.f - 2.f * __builtin_amdgcn_rcpf(1.f + __builtin_amdgcn_exp2f(2.8853900817779268f * x));
}

// ================= pack kernel =================
__global__ void pack_kernel(const float* __restrict__ in0, const float* __restrict__ Wih0,
                            const float* __restrict__ Whh0, const float* __restrict__ bih0, const float* __restrict__ bhh0,
                            const float* __restrict__ Wih1, const float* __restrict__ Whh1, const float* __restrict__ bih1, const float* __restrict__ bhh1,
                            const float* __restrict__ Wih2, const float* __restrict__ Whh2, const float* __restrict__ bih2, const float* __restrict__ bhh2,
                            f16* __restrict__ xf, f16* __restrict__ wp0,
                            f16* __restrict__ whhf, f16* __restrict__ wihf, float* __restrict__ bc)
{
  const int stride = gridDim.x * blockDim.x;
  const int tid0 = blockIdx.x * blockDim.x + threadIdx.x;

  // xf: [B][T][FW], zero-pad f >= 65
  const int NX = B_ * T_ * FW;
  for (int i = tid0; i < NX; i += stride) {
    int f = i % FW; int bt = i / FW;
    float v = (f < IN_) ? in0[(size_t)bt * IN_ + f] : 0.f;
    xf[i] = (f16)v;
  }
  // wp0: [kc][nt][lane][8] ; k' = kc*32 + (l>>4)*8 + j ; g = nt*16 + (l&15)
  const int NW0 = KC0 * 16 * 64 * 8;
  for (int i = tid0; i < NW0; i += stride) {
    int j = i & 7, l = (i >> 3) & 63, nt = (i >> 9) & 15, kc = i >> 13;
    int kp = kc * 32 + ((l >> 4) * 8 + j);
    int g  = nt * 16 + (l & 15);
    int d = kp / FW, f = kp % FW;
    float v = (kp < 1800 && f < IN_) ? Wih0[(size_t)g * 1625 + d * IN_ + f] : 0.f;
    wp0[i] = (f16)v;
  }
  // whhf (r_kernel layout): per layer, frag tt = w*4+u, kf:
  //   g = u*64 + w*16 + (l&15) ; k = kf*32 + (l>>4)*8 + e
  const float* whhs[3] = {Whh0, Whh1, Whh2};
  for (int i = tid0; i < 3 * 16384; i += stride) {
    int L = i >> 14, r = i & 16383;
    int e = r & 7, l = (r >> 3) & 63, kf = (r >> 9) & 1, tt = (r >> 10) & 15;
    int wv = tt >> 2, u = tt & 3;
    int g = u * 64 + wv * 16 + (l & 15);
    int k = kf * 32 + ((l >> 4) * 8) + e;
    whhf[i] = (f16)whhs[L][g * 64 + k];
  }
  // wihf: per layer [kc][nt][lane][8]: B[k][n] = Wih[n][k], K=64  (g_kernel layout, unchanged)
  const float* wihs[2] = {Wih1, Wih2};
  for (int i = tid0; i < 2 * 16384; i += stride) {
    int L = i >> 14, r = i & 16383;
    int j = r & 7, l = (r >> 3) & 63, nt = (r >> 9) & 15, kc = r >> 13;
    int k = kc * 32 + ((l >> 4) * 8 + j);
    int g = nt * 16 + (l & 15);
    wihf[i] = (f16)wihs[L][g * 64 + k];
  }
  // combined biases
  const float* bis[3] = {bih0, bih1, bih2};
  const float* bhs[3] = {bhh0, bhh1, bhh2};
  for (int i = tid0; i < 3 * 256; i += stride) {
    int L = i >> 8, g = i & 255;
    bc[i] = bis[L][g] + bhs[L][g];
  }
}

// ================= layer-0 windowed GEMM =================
// grid (32, 16): x = t-tile (64 rows), y = batch. 256 threads = 4 waves.
__global__ __launch_bounds__(256) void gemm0_kernel(const f16* __restrict__ xf, const f16* __restrict__ wp0,
                                                    const float* __restrict__ bc0, float* __restrict__ pre)
{
  __shared__ __align__(16) f16 frames[90 * FW];   // 12,960 B
  __shared__ __align__(16) f16 bbuf[16 * 64 * 8]; // 16,384 B
  const int tid = threadIdx.x, l = tid & 63, w = tid >> 6;
  const int b = blockIdx.y, t0 = blockIdx.x * 64;

  // zero frames (covers t-edge padding and the k'>=1800 tail rows)
  for (int c = tid; c < 810; c += 256) *(f32x4*)(&frames[c * 8]) = (f32x4)0.f;
  __syncthreads();

  // stage valid frame range [s0, s1) of this batch
  {
    const int st = t0 - 12;
    const int s0 = st < 0 ? 0 : st;
    const int s1 = (t0 + 78) < T_ ? (t0 + 78) : T_;
    const int dstrow = s0 - st;
    const int nchunk = (s1 - s0) * 9;  // 16B chunks (144 B/row)
    const f16* gsrc = xf + ((size_t)b * T_ + s0) * FW;
    for (int base = 0; base < 810; base += 256) {
      int idx = base + w * 64 + l;
      if (idx < nchunk) {
        char* ldsb = (char*)frames + dstrow * 144 + (base + w * 64) * 16;
        async_copy16((const char*)gsrc + (size_t)(base + w * 64) * 16 + l * 16, ldsb);
      }
    }
  }

  f32x4 acc[16];
#pragma unroll
  for (int i = 0; i < 16; ++i) acc[i] = (f32x4)0.f;

  for (int kc = 0; kc < KC0; ++kc) {
    __syncthreads();  // drains previous loads/reads; protects bbuf
    const f16* wsrc = wp0 + (size_t)kc * 8192;
#pragma unroll
    for (int i = 0; i < 4; ++i) {
      char* ldsb = (char*)bbuf + (i * 256 + w * 64) * 16;
      async_copy16((const char*)wsrc + (size_t)(i * 256 + w * 64 + l) * 16, ldsb);
    }
    __syncthreads();  // vmcnt(0) drain -> bbuf ready

    int kp0 = kc * 32 + ((l >> 4) * 8);
    int d = kp0 / FW, f = kp0 % FW;
    int r = w * 16 + (l & 15);
    half8 af = *(const half8*)(&frames[(r + d) * FW + f]);
#pragma unroll
    for (int nt = 0; nt < 16; ++nt) {
      half8 bf = *(const half8*)(&bbuf[(nt * 64 + l) * 8]);
      acc[nt] = __builtin_amdgcn_mfma_f32_16x16x32_f16(af, bf, acc[nt], 0, 0, 0);
    }
  }

  // epilogue: bias + permuted/swizzled store into pre[t][b][...]
  const int n_ = l & 15, grp = l >> 4;
#pragma unroll
  for (int nt = 0; nt < 16; ++nt) {
    int g = nt * 16 + n_;
    float bias = bc0[g];
    int colByte = pre_col_byte(b, g);
#pragma unroll
    for (int rr = 0; rr < 4; ++rr) {
      int t = t0 + w * 16 + grp * 4 + rr;
      *(float*)((char*)pre + (size_t)t * 16384 + (size_t)b * 1024 + colByte) = acc[nt][rr] + bias;
    }
  }
}

// ================= inter-layer GEMM (pre = h_prev @ WihT + bias) =================
// grid (32, 16), 512 threads = 8 waves: wave = (ms = w&3 [M-subtile], nh = w>>2 [N-half])
__global__ __launch_bounds__(512) void g_kernel(const f16* __restrict__ hprev, const f16* __restrict__ wpf,
                                                const float* __restrict__ bcL, float* __restrict__ pre)
{
  __shared__ __align__(16) f16 albuf[64 * 64];  // 8 KB, XOR-swizzled rows
  const int tid = threadIdx.x, l = tid & 63, w = tid >> 6;
  const int b = blockIdx.y, t0 = blockIdx.x * 64;
  const int ms = w & 3, nh = w >> 2;

  // reg-stage A with swizzled ds_write (16B per thread)
  {
    const char* src = (const char*)(hprev + ((size_t)b * T_ + t0) * HID);
    f32x4 v = *(const f32x4*)(src + (size_t)tid * 16);
    int r = tid >> 3, s = tid & 7;
    *(f32x4*)((char*)albuf + r * 128 + ((s * 16) ^ ((r & 7) << 4))) = v;
  }
  __syncthreads();

  // B fragments direct global->VGPR
  half8 bf[8][2];
#pragma unroll
  for (int i = 0; i < 8; ++i) {
    int nt = nh * 8 + i;
#pragma unroll
    for (int kc = 0; kc < 2; ++kc)
      bf[i][kc] = *(const half8*)(wpf + (((size_t)kc * 16 + nt) * 64 + l) * 8);
  }
  // A fragments (swizzled read)
  half8 af[2];
#pragma unroll
  for (int kc = 0; kc < 2; ++kc) {
    int r = ms * 16 + (l & 15);
    int kbyte = kc * 64 + ((l >> 4) * 16);
    af[kc] = *(const half8*)((const char*)albuf + r * 128 + (kbyte ^ ((r & 7) << 4)));
  }

  f32x4 acc[8];
#pragma unroll
  for (int i = 0; i < 8; ++i) {
    acc[i] = __builtin_amdgcn_mfma_f32_16x16x32_f16(af[0], bf[i][0], (f32x4)0.f, 0, 0, 0);
    acc[i] = __builtin_amdgcn_mfma_f32_16x16x32_f16(af[1], bf[i][1], acc[i], 0, 0, 0);
  }

  const int n_ = l & 15, grp = l >> 4;
#pragma unroll
  for (int i = 0; i < 8; ++i) {
    int g = (nh * 8 + i) * 16 + n_;
    float bias = bcL[g];
    int colByte = pre_col_byte(b, g);
#pragma unroll
    for (int rr = 0; rr < 4; ++rr) {
      int t = t0 + ms * 16 + grp * 4 + rr;
      *(float*)((char*)pre + (size_t)t * 16384 + (size_t)b * 1024 + colByte) = acc[i][rr] + bias;
    }
  }
}

// ================= LSTM recurrence (one layer, 4 batches per block, grid=4) =================
// 256 threads = 4 waves. A is built with each batch's h replicated 4x in the M dim
// (row = b*4 + jq, A[row][k] = h[row>>2][k]); C is then independent of row&3, so
// lane (grp,n) reg 0 of N-tile u holds gate u of (b=grp, j=w*16+n): one c-update
// per lane across ALL 64 lanes, zero redistribution.
__global__ __launch_bounds__(256) void r_kernel(const float* __restrict__ pre, const f16* __restrict__ whhf,
                                                f16* __restrict__ hout)
{
  __shared__ __align__(16) char lds[4 * 4096 + 2 * 512];  // 17 KB: pre ring + H ping-pong
  char* ring = lds;
  char* Hb   = lds + 16384;
  const int tid = threadIdx.x, l = tid & 63, w = tid >> 6;
  const int n_ = l & 15, grp = l >> 4;
  const int b0 = blockIdx.x * 4;
  const int j = w * 16 + n_;       // gate-phase column
  const int bglob = b0 + grp;      // gate-phase batch
  const int arow = (l & 15) >> 2;  // MFMA A-fragment source batch (replicated rows)

  // recurrent weight fragments: frag tt=(w*4+u), kf -> g = u*64 + w*16 + (l&15)
  half8 bf[4][2];
#pragma unroll
  for (int u = 0; u < 4; ++u)
#pragma unroll
    for (int kf = 0; kf < 2; ++kf)
      bf[u][kf] = *(const half8*)(whhf + ((((size_t)(w * 4 + u) * 2) + kf) << 9) + (l << 3));

  // zero both H buffers (1 KB)
  if (tid < 64) *(f32x4*)(Hb + tid * 16) = (f32x4)0.f;
  float c = 0.f;

  // prologue: prefetch pre slots 0..2 (1 KB per wave per slot = this block's 4 batches)
#pragma unroll
  for (int s = 0; s < 3; ++s)
    async_copy16((const char*)pre + (size_t)s * 16384 + b0 * 1024 + w * 1024 + l * 16,
                 ring + s * 4096 + w * 1024 + l * 16);

  int cur = 0;
  for (int t = 0; t < T_; ++t) {
    // sync 1: H[cur] ds_writes (and prologue zeros) visible to all waves
    asm volatile("s_waitcnt lgkmcnt(0)" ::: "memory");
    __builtin_amdgcn_s_barrier();
    __builtin_amdgcn_sched_barrier(0);

    // MFMA phase: G = repl(H[cur]) @ WhhT
    char* Hc = Hb + cur * 512;
    half8 af[2];
#pragma unroll
    for (int kf = 0; kf < 2; ++kf)
      af[kf] = *(const half8*)(Hc + arow * 128 + kf * 64 + grp * 16);
    f32x4 acc[4];
#pragma unroll
    for (int u = 0; u < 4; ++u) {
      acc[u] = __builtin_amdgcn_mfma_f32_16x16x32_f16(af[0], bf[u][0], (f32x4)0.f, 0, 0, 0);
      acc[u] = __builtin_amdgcn_mfma_f32_16x16x32_f16(af[1], bf[u][1], acc[u], 0, 0, 0);
    }

    // sync 2: pre slot t staged. Counted vmcnt: per step, 1 store (hout) + 1 load
    // (prefetch) per wave; slot-t load was issued at step t-3 -> <=4 younger VMEM
    // ops at this point (either S/L order within a step), so vmcnt(4) retires it.
    if (t == 0)      asm volatile("s_waitcnt vmcnt(2)" ::: "memory");
    else if (t == 1) asm volatile("s_waitcnt vmcnt(3)" ::: "memory");
    else             asm volatile("s_waitcnt vmcnt(4)" ::: "memory");
    __builtin_amdgcn_s_barrier();
    __builtin_amdgcn_sched_barrier(0);

    // gate phase: one c-update per lane
    const char* slot = ring + (t & 3) * 4096;
    f32x4 p = *(const f32x4*)(slot + grp * 1024 + ((j << 4) ^ ((bglob & 7) << 4)));
    float iv = acc[0][0] + p.x;
    float fv = acc[1][0] + p.y;
    float gv = acc[2][0] + p.z;
    float ov = acc[3][0] + p.w;
    c = fsig(fv) * c + fsig(iv) * ftanh(gv);
    float hv = fsig(ov) * ftanh(c);
    f16 h16 = (f16)hv;
    char* Hn = Hb + (cur ^ 1) * 512;
    *(f16*)(Hn + grp * 128 + j * 2) = h16;
    hout[((size_t)bglob * T_ + t) * HID + j] = h16;

    // prefetch slot t+3 (dummy tail load keeps VMEM-op accounting uniform;
    // its dest slot (t-1)&3 is already consumed)
    {
      int tp = (t + 3 < T_) ? (t + 3) : 0;
      async_copy16((const char*)pre + (size_t)tp * 16384 + b0 * 1024 + w * 1024 + l * 16,
                   ring + ((t + 3) & 3) * 4096 + w * 1024 + l * 16);
    }
    cur ^= 1;
  }
}

// ================= final projection =================
__global__ __launch_bounds__(256) void fin_kernel(const f16* __restrict__ h2, const float* __restrict__ Wout,
                                                  const float* __restrict__ bout, float* __restrict__ out)
{
  __shared__ float wl[64];
  const int tid = threadIdx.x;
  if (tid < 64) wl[tid] = Wout[tid];
  __syncthreads();
  const int idx = blockIdx.x * 256 + tid;  // = b*T + t
  const f16* hr = h2 + (size_t)idx * HID;
  float acc = bout[0];
#pragma unroll
  for (int i = 0; i < 64; i += 8) {
    half8 hv = *(const half8*)(hr + i);
#pragma unroll
    for (int k = 0; k < 8; ++k) {
      float h = (float)hv[k];
      h = fmaxf(h, 0.f);
      acc += h * wl[i + k];
    }
  }
  out[idx] = fsig(acc);
}

// ================= launcher =================
extern "C" void kernel_launch(void* const* d_in, const int* in_sizes, int n_in,
                              void* d_out, int out_size, void* d_ws, size_t ws_size,
                              hipStream_t stream)
{
  (void)in_sizes; (void)n_in; (void)out_size; (void)ws_size;
  const float* in0  = (const float*)d_in[0];
  const float* Wih0 = (const float*)d_in[1];
  const float* Whh0 = (const float*)d_in[2];
  const float* bih0 = (const float*)d_in[3];
  const float* bhh0 = (const float*)d_in[4];
  const float* Wih1 = (const float*)d_in[5];
  const float* Whh1 = (const float*)d_in[6];
  const float* bih1 = (const float*)d_in[7];
  const float* bhh1 = (const float*)d_in[8];
  const float* Wih2 = (const float*)d_in[9];
  const float* Whh2 = (const float*)d_in[10];
  const float* bih2 = (const float*)d_in[11];
  const float* bhh2 = (const float*)d_in[12];
  const float* Wout = (const float*)d_in[13];
  const float* bout = (const float*)d_in[14];
  float* out = (float*)d_out;

  char* ws = (char*)d_ws;
  f16*   xf   = (f16*)(ws + OFF_XF);
  f16*   wp0  = (f16*)(ws + OFF_WP0);
  f16*   whhf = (f16*)(ws + OFF_WHHF);
  f16*   wihf = (f16*)(ws + OFF_WIHF);
  float* bc   = (float*)(ws + OFF_BC);
  float* pre  = (float*)(ws + OFF_PRE);
  f16*   h0   = (f16*)(ws + OFF_H0);
  f16*   h1   = (f16*)(ws + OFF_H1);
  f16*   h2   = (f16*)(ws + OFF_H2);

  pack_kernel<<<256, 256, 0, stream>>>(in0, Wih0, Whh0, bih0, bhh0,
                                       Wih1, Whh1, bih1, bhh1,
                                       Wih2, Whh2, bih2, bhh2,
                                       xf, wp0, whhf, wihf, bc);
  gemm0_kernel<<<dim3(32, 16), 256, 0, stream>>>(xf, wp0, bc, pre);
  r_kernel<<<4, 256, 0, stream>>>(pre, whhf, h0);
  g_kernel<<<dim3(32, 16), 512, 0, stream>>>(h0, wihf, bc + 256, pre);
  r_kernel<<<4, 256, 0, stream>>>(pre, whhf + 16384, h1);
  g_kernel<<<dim3(32, 16), 512, 0, stream>>>(h1, wihf + 16384, bc + 512, pre);
  r_kernel<<<4, 256, 0, stream>>>(pre, whhf + 32768, h2);
  fin_kernel<<<128, 256, 0, stream>>>(h2, Wout, bout, out);
}

// Round 3
// 1697.258 us; speedup vs baseline: 2.7886x; 1.5215x over previous
//
#include <hip/hip_runtime.h>
#include <stdint.h>

#define GLOBAL_AS __attribute__((address_space(1)))
#define LDS_AS    __attribute__((address_space(3)))

typedef _Float16 f16;
typedef _Float16 half8 __attribute__((ext_vector_type(8)));
typedef float    f32x4 __attribute__((ext_vector_type(4)));

constexpr int B_  = 16;
constexpr int T_  = 2048;
constexpr int IN_ = 65;
constexpr int HID = 64;
constexpr int G4  = 256;      // 4*HID
constexpr int FW  = 72;       // padded frame width (25*72 = 1800)
constexpr int KP  = 1824;     // padded K for layer0 (57*32)
constexpr int KC0 = KP / 32;  // 57

// ---- workspace layout (bytes) ----
constexpr size_t OFF_XF   = 0;                          // [B][T][FW] f16
constexpr size_t SZ_XF    = (size_t)B_ * T_ * FW * 2;   // 4,718,592
constexpr size_t OFF_WP0  = OFF_XF + SZ_XF;             // [KC0][16][64][8] f16
constexpr size_t SZ_WP0   = (size_t)KC0 * 16 * 64 * 8 * 2;
constexpr size_t OFF_WHHF = OFF_WP0 + SZ_WP0;           // 3 x r-layout frags
constexpr size_t SZ_WHHF1 = (size_t)16 * 2 * 64 * 8 * 2;
constexpr size_t OFF_WIHR = OFF_WHHF + 3 * SZ_WHHF1;    // 2 x r-layout frags (Wih1, Wih2)
constexpr size_t SZ_WIHR1 = (size_t)16 * 2 * 64 * 8 * 2;
constexpr size_t OFF_BC   = OFF_WIHR + 2 * SZ_WIHR1;    // 3 x [256] f32
constexpr size_t OFF_PRE  = ((OFF_BC + 3 * 256 * 4 + 1023) / 1024) * 1024;  // [T][B][256] f32 (permuted+swizzled), layer 0 only
constexpr size_t SZ_PRE   = (size_t)T_ * B_ * G4 * 4;   // 33,554,432
constexpr size_t OFF_H2   = OFF_PRE + SZ_PRE;           // [B][T][HID] f16 (final layer h only)
constexpr size_t SZ_H     = (size_t)B_ * T_ * HID * 2;  // 4,194,304

__device__ __forceinline__ void async_copy16(const void* g, void* l) {
  __builtin_amdgcn_global_load_lds((const GLOBAL_AS void*)g, (LDS_AS void*)l, 16, 0, 0);
}

// within-row byte offset for pre[t][b][g]: permute g=(q*64+j) -> (j*16|q*4), XOR-swizzle by batch
__device__ __forceinline__ int pre_col_byte(int b, int g) {
  int j = g & 63, q = g >> 6;
  return ((j << 4) | (q << 2)) ^ ((b & 7) << 4);
}

__device__ __forceinline__ float fsig(float x) {
  return __builtin_amdgcn_rcpf(1.f + __builtin_amdgcn_exp2f(-1.4426950408889634f * x));
}
__device__ __forceinline__ float ftanh(float x) {
  return 1.f - 2.f * __builtin_amdgcn_rcpf(1.f + __builtin_amdgcn_exp2f(2.8853900817779268f * x));
}

// ================= pack kernel =================
__global__ void pack_kernel(const float* __restrict__ in0, const float* __restrict__ Wih0,
                            const float* __restrict__ Whh0, const float* __restrict__ bih0, const float* __restrict__ bhh0,
                            const float* __restrict__ Wih1, const float* __restrict__ Whh1, const float* __restrict__ bih1, const float* __restrict__ bhh1,
                            const float* __restrict__ Wih2, const float* __restrict__ Whh2, const float* __restrict__ bih2, const float* __restrict__ bhh2,
                            f16* __restrict__ xf, f16* __restrict__ wp0,
                            f16* __restrict__ whhf, f16* __restrict__ wihr, float* __restrict__ bc)
{
  const int stride = gridDim.x * blockDim.x;
  const int tid0 = blockIdx.x * blockDim.x + threadIdx.x;

  // xf: [B][T][FW], zero-pad f >= 65
  const int NX = B_ * T_ * FW;
  for (int i = tid0; i < NX; i += stride) {
    int f = i % FW; int bt = i / FW;
    float v = (f < IN_) ? in0[(size_t)bt * IN_ + f] : 0.f;
    xf[i] = (f16)v;
  }
  // wp0: [kc][nt][lane][8] ; k' = kc*32 + (l>>4)*8 + j ; g = nt*16 + (l&15)
  const int NW0 = KC0 * 16 * 64 * 8;
  for (int i = tid0; i < NW0; i += stride) {
    int j = i & 7, l = (i >> 3) & 63, nt = (i >> 9) & 15, kc = i >> 13;
    int kp = kc * 32 + ((l >> 4) * 8 + j);
    int g  = nt * 16 + (l & 15);
    int d = kp / FW, f = kp % FW;
    float v = (kp < 1800 && f < IN_) ? Wih0[(size_t)g * 1625 + d * IN_ + f] : 0.f;
    wp0[i] = (f16)v;
  }
  // whhf (r-layout): per layer, frag tt = wv*4+u, kf:
  //   g = u*64 + wv*16 + (l&15) ; k = kf*32 + (l>>4)*8 + e
  const float* whhs[3] = {Whh0, Whh1, Whh2};
  for (int i = tid0; i < 3 * 16384; i += stride) {
    int L = i >> 14, r = i & 16383;
    int e = r & 7, l = (r >> 3) & 63, kf = (r >> 9) & 1, tt = (r >> 10) & 15;
    int wv = tt >> 2, u = tt & 3;
    int g = u * 64 + wv * 16 + (l & 15);
    int k = kf * 32 + ((l >> 4) * 8) + e;
    whhf[i] = (f16)whhs[L][g * 64 + k];
  }
  // wihr (r-layout, same formula) from Wih1/Wih2 (both [256][64])
  const float* wihs[2] = {Wih1, Wih2};
  for (int i = tid0; i < 2 * 16384; i += stride) {
    int L = i >> 14, r = i & 16383;
    int e = r & 7, l = (r >> 3) & 63, kf = (r >> 9) & 1, tt = (r >> 10) & 15;
    int wv = tt >> 2, u = tt & 3;
    int g = u * 64 + wv * 16 + (l & 15);
    int k = kf * 32 + ((l >> 4) * 8) + e;
    wihr[i] = (f16)wihs[L][g * 64 + k];
  }
  // combined biases
  const float* bis[3] = {bih0, bih1, bih2};
  const float* bhs[3] = {bhh0, bhh1, bhh2};
  for (int i = tid0; i < 3 * 256; i += stride) {
    int L = i >> 8, g = i & 255;
    bc[i] = bis[L][g] + bhs[L][g];
  }
}

// ================= layer-0 windowed GEMM =================
// grid (32, 16): x = t-tile (64 rows), y = batch. 256 threads = 4 waves.
__global__ __launch_bounds__(256) void gemm0_kernel(const f16* __restrict__ xf, const f16* __restrict__ wp0,
                                                    const float* __restrict__ bc0, float* __restrict__ pre)
{
  __shared__ __align__(16) f16 frames[90 * FW];   // 12,960 B
  __shared__ __align__(16) f16 bbuf[16 * 64 * 8]; // 16,384 B
  const int tid = threadIdx.x, l = tid & 63, w = tid >> 6;
  const int b = blockIdx.y, t0 = blockIdx.x * 64;

  // zero frames (covers t-edge padding and the k'>=1800 tail rows)
  for (int c = tid; c < 810; c += 256) *(f32x4*)(&frames[c * 8]) = (f32x4)0.f;
  __syncthreads();

  // stage valid frame range [s0, s1) of this batch
  {
    const int st = t0 - 12;
    const int s0 = st < 0 ? 0 : st;
    const int s1 = (t0 + 78) < T_ ? (t0 + 78) : T_;
    const int dstrow = s0 - st;
    const int nchunk = (s1 - s0) * 9;  // 16B chunks (144 B/row)
    const f16* gsrc = xf + ((size_t)b * T_ + s0) * FW;
    for (int base = 0; base < 810; base += 256) {
      int idx = base + w * 64 + l;
      if (idx < nchunk) {
        char* ldsb = (char*)frames + dstrow * 144 + (base + w * 64) * 16;
        async_copy16((const char*)gsrc + (size_t)(base + w * 64) * 16 + l * 16, ldsb);
      }
    }
  }

  f32x4 acc[16];
#pragma unroll
  for (int i = 0; i < 16; ++i) acc[i] = (f32x4)0.f;

  for (int kc = 0; kc < KC0; ++kc) {
    __syncthreads();  // drains previous loads/reads; protects bbuf
    const f16* wsrc = wp0 + (size_t)kc * 8192;
#pragma unroll
    for (int i = 0; i < 4; ++i) {
      char* ldsb = (char*)bbuf + (i * 256 + w * 64) * 16;
      async_copy16((const char*)wsrc + (size_t)(i * 256 + w * 64 + l) * 16, ldsb);
    }
    __syncthreads();  // vmcnt(0) drain -> bbuf ready

    int kp0 = kc * 32 + ((l >> 4) * 8);
    int d = kp0 / FW, f = kp0 % FW;
    int r = w * 16 + (l & 15);
    half8 af = *(const half8*)(&frames[(r + d) * FW + f]);
#pragma unroll
    for (int nt = 0; nt < 16; ++nt) {
      half8 bf = *(const half8*)(&bbuf[(nt * 64 + l) * 8]);
      acc[nt] = __builtin_amdgcn_mfma_f32_16x16x32_f16(af, bf, acc[nt], 0, 0, 0);
    }
  }

  // epilogue: bias + permuted/swizzled store into pre[t][b][...]
  const int n_ = l & 15, grp = l >> 4;
#pragma unroll
  for (int nt = 0; nt < 16; ++nt) {
    int g = nt * 16 + n_;
    float bias = bc0[g];
    int colByte = pre_col_byte(b, g);
#pragma unroll
    for (int rr = 0; rr < 4; ++rr) {
      int t = t0 + w * 16 + grp * 4 + rr;
      *(float*)((char*)pre + (size_t)t * 16384 + (size_t)b * 1024 + colByte) = acc[nt][rr] + bias;
    }
  }
}

// ================= fused 3-layer LSTM recurrence =================
// grid = 4 blocks x 768 threads (12 waves). Wave-group L = waves 4L..4L+3 runs
// layer L at time t_L = s - L (software pipeline, skew 1 step/layer).
// h handoff between groups via 2-slot LDS rings; pre for layers 1,2 computed
// in-kernel as 8 extra replicated-A MFMAs vs Wih (r-layout frags) + bias.
__global__ __launch_bounds__(768) void r3_kernel(const float* __restrict__ pre,
                                                 const f16* __restrict__ whhf,
                                                 const f16* __restrict__ wihr,
                                                 const float* __restrict__ bc,
                                                 f16* __restrict__ h2out)
{
  __shared__ __align__(16) char ring[4 * 4096];   // pre0 stream, 4 slots
  __shared__ __align__(16) char hring[6 * 640];   // h rings: [layer][slot] 4 batches x 160 B
  const int tid = threadIdx.x, l = tid & 63, w = tid >> 6;
  const int L = w >> 2, wv = w & 3;
  const int n_ = l & 15, grp = l >> 4;
  const int b0 = blockIdx.x * 4;
  const int j = wv * 16 + n_;       // hidden index this lane updates
  const int bglob = b0 + grp;       // batch this lane updates
  const int arow = n_ >> 2;         // A-frag source batch (replicated rows)

  // recurrent (Whh) fragments, r-layout
  half8 bfh[4][2];
  const f16* wh = whhf + (size_t)L * 16384;
#pragma unroll
  for (int u = 0; u < 4; ++u)
#pragma unroll
    for (int kf = 0; kf < 2; ++kf)
      bfh[u][kf] = *(const half8*)(wh + (((wv * 4 + u) * 2 + kf) << 9) + (l << 3));

  // input (Wih) fragments for layers 1,2
  half8 bfx[4][2];
  if (L > 0) {
    const f16* wx = wihr + (size_t)(L - 1) * 16384;
#pragma unroll
    for (int u = 0; u < 4; ++u)
#pragma unroll
      for (int kf = 0; kf < 2; ++kf)
        bfx[u][kf] = *(const half8*)(wx + (((wv * 4 + u) * 2 + kf) << 9) + (l << 3));
  }

  float bi[4] = {0.f, 0.f, 0.f, 0.f};
  if (L > 0) {
#pragma unroll
    for (int u = 0; u < 4; ++u) bi[u] = bc[L * 256 + u * 64 + j];
  }

  // zero h rings (3840 B)
  for (int i = tid; i < 240; i += 768) *(f32x4*)(hring + i * 16) = (f32x4)0.f;
  float c = 0.f;

  // prologue: group 0 prefetches pre slots 0..2 (1 KB per wave per slot)
  if (L == 0) {
#pragma unroll
    for (int s = 0; s < 3; ++s)
      async_copy16((const char*)pre + (size_t)s * 16384 + b0 * 1024 + wv * 1024 + l * 16,
                   ring + s * 4096 + wv * 1024 + l * 16);
  }

  for (int s = 0; s < T_ + 2; ++s) {
    // barrier 1: previous step's h ds_writes (and prologue zeros) visible
    asm volatile("s_waitcnt lgkmcnt(0)" ::: "memory");
    __builtin_amdgcn_s_barrier();
    __builtin_amdgcn_sched_barrier(0);

    const int t = s - L;
    const bool act = (unsigned)t < (unsigned)T_;

    f32x4 acc[4];
    if (act) {
      // own recurrent state h_L[t-1], slot (t-1)&1
      const char* Hc = hring + (L * 2 + ((t + 1) & 1)) * 640;
      half8 a0 = *(const half8*)(Hc + arow * 160 + grp * 16);
      half8 a1 = *(const half8*)(Hc + arow * 160 + 64 + grp * 16);
#pragma unroll
      for (int u = 0; u < 4; ++u) {
        acc[u] = __builtin_amdgcn_mfma_f32_16x16x32_f16(a0, bfh[u][0], (f32x4)0.f, 0, 0, 0);
        acc[u] = __builtin_amdgcn_mfma_f32_16x16x32_f16(a1, bfh[u][1], acc[u], 0, 0, 0);
      }
      if (L > 0) {
        // input h_{L-1}[t], slot t&1 (written by group L-1 last step)
        const char* Xc = hring + ((L - 1) * 2 + (t & 1)) * 640;
        half8 x0 = *(const half8*)(Xc + arow * 160 + grp * 16);
        half8 x1 = *(const half8*)(Xc + arow * 160 + 64 + grp * 16);
#pragma unroll
        for (int u = 0; u < 4; ++u) {
          acc[u] = __builtin_amdgcn_mfma_f32_16x16x32_f16(x0, bfx[u][0], acc[u], 0, 0, 0);
          acc[u] = __builtin_amdgcn_mfma_f32_16x16x32_f16(x1, bfx[u][1], acc[u], 0, 0, 0);
        }
      }
    }

    // barrier 2: group 0's pre slot staged (uniform counted vmcnt(2):
    // 1 load/step/wave, slot t issued at step t-3, prologue covers warmup)
    if (L == 0 && act) asm volatile("s_waitcnt vmcnt(2)" ::: "memory");
    __builtin_amdgcn_s_barrier();
    __builtin_amdgcn_sched_barrier(0);

    if (act) {
      float iv, fv, gv, ov;
      if (L == 0) {
        const char* slot = ring + (t & 3) * 4096;
        f32x4 p = *(const f32x4*)(slot + grp * 1024 + ((j << 4) ^ ((bglob & 7) << 4)));
        iv = acc[0][0] + p.x; fv = acc[1][0] + p.y; gv = acc[2][0] + p.z; ov = acc[3][0] + p.w;
      } else {
        iv = acc[0][0] + bi[0]; fv = acc[1][0] + bi[1]; gv = acc[2][0] + bi[2]; ov = acc[3][0] + bi[3];
      }
      c = fsig(fv) * c + fsig(iv) * ftanh(gv);
      float hv = fsig(ov) * ftanh(c);
      f16 h16 = (f16)hv;
      *(f16*)(hring + (L * 2 + (t & 1)) * 640 + grp * 160 + j * 2) = h16;
      if (L == 2) h2out[((size_t)bglob * T_ + t) * HID + j] = h16;
      if (L == 0) {
        int tp = (t + 3 < T_) ? (t + 3) : 0;  // clamped dummy at tail keeps vmcnt uniform
        async_copy16((const char*)pre + (size_t)tp * 16384 + b0 * 1024 + wv * 1024 + l * 16,
                     ring + ((t + 3) & 3) * 4096 + wv * 1024 + l * 16);
      }
    }
  }
}

// ================= final projection =================
__global__ __launch_bounds__(256) void fin_kernel(const f16* __restrict__ h2, const float* __restrict__ Wout,
                                                  const float* __restrict__ bout, float* __restrict__ out)
{
  __shared__ float wl[64];
  const int tid = threadIdx.x;
  if (tid < 64) wl[tid] = Wout[tid];
  __syncthreads();
  const int idx = blockIdx.x * 256 + tid;  // = b*T + t
  const f16* hr = h2 + (size_t)idx * HID;
  float acc = bout[0];
#pragma unroll
  for (int i = 0; i < 64; i += 8) {
    half8 hv = *(const half8*)(hr + i);
#pragma unroll
    for (int k = 0; k < 8; ++k) {
      float h = (float)hv[k];
      h = fmaxf(h, 0.f);
      acc += h * wl[i + k];
    }
  }
  out[idx] = fsig(acc);
}

// ================= launcher =================
extern "C" void kernel_launch(void* const* d_in, const int* in_sizes, int n_in,
                              void* d_out, int out_size, void* d_ws, size_t ws_size,
                              hipStream_t stream)
{
  (void)in_sizes; (void)n_in; (void)out_size; (void)ws_size;
  const float* in0  = (const float*)d_in[0];
  const float* Wih0 = (const float*)d_in[1];
  const float* Whh0 = (const float*)d_in[2];
  const float* bih0 = (const float*)d_in[3];
  const float* bhh0 = (const float*)d_in[4];
  const float* Wih1 = (const float*)d_in[5];
  const float* Whh1 = (const float*)d_in[6];
  const float* bih1 = (const float*)d_in[7];
  const float* bhh1 = (const float*)d_in[8];
  const float* Wih2 = (const float*)d_in[9];
  const float* Whh2 = (const float*)d_in[10];
  const float* bih2 = (const float*)d_in[11];
  const float* bhh2 = (const float*)d_in[12];
  const float* Wout = (const float*)d_in[13];
  const float* bout = (const float*)d_in[14];
  float* out = (float*)d_out;

  char* ws = (char*)d_ws;
  f16*   xf   = (f16*)(ws + OFF_XF);
  f16*   wp0  = (f16*)(ws + OFF_WP0);
  f16*   whhf = (f16*)(ws + OFF_WHHF);
  f16*   wihr = (f16*)(ws + OFF_WIHR);
  float* bc   = (float*)(ws + OFF_BC);
  float* pre  = (float*)(ws + OFF_PRE);
  f16*   h2   = (f16*)(ws + OFF_H2);

  pack_kernel<<<256, 256, 0, stream>>>(in0, Wih0, Whh0, bih0, bhh0,
                                       Wih1, Whh1, bih1, bhh1,
                                       Wih2, Whh2, bih2, bhh2,
                                       xf, wp0, whhf, wihr, bc);
  gemm0_kernel<<<dim3(32, 16), 256, 0, stream>>>(xf, wp0, bc, pre);
  r3_kernel<<<4, 768, 0, stream>>>(pre, whhf, wihr, bc, h2);
  fin_kernel<<<128, 256, 0, stream>>>(h2, Wout, bout, out);
}

// Round 4
// 1427.261 us; speedup vs baseline: 3.3161x; 1.1892x over previous
//
#include <hip/hip_runtime.h>
#include <stdint.h>

#define GLOBAL_AS __attribute__((address_space(1)))
#define LDS_AS    __attribute__((address_space(3)))

typedef _Float16 f16;
typedef _Float16 half8 __attribute__((ext_vector_type(8)));
typedef float    f32x4 __attribute__((ext_vector_type(4)));

constexpr int B_  = 16;
constexpr int T_  = 2048;
constexpr int IN_ = 65;
constexpr int HID = 64;
constexpr int G4  = 256;      // 4*HID
constexpr int FW  = 72;       // padded frame width (25*72 = 1800)
constexpr int KP  = 1824;     // padded K for layer0 (57*32)
constexpr int KC0 = KP / 32;  // 57

// ---- workspace layout (bytes) ----
constexpr size_t OFF_XF   = 0;                          // [B][T][FW] f16
constexpr size_t SZ_XF    = (size_t)B_ * T_ * FW * 2;   // 4,718,592
constexpr size_t OFF_WP0  = OFF_XF + SZ_XF;             // [KC0][16][64][8] f16
constexpr size_t SZ_WP0   = (size_t)KC0 * 16 * 64 * 8 * 2;
constexpr size_t OFF_WHHF = OFF_WP0 + SZ_WP0;           // 3 x r-layout frags
constexpr size_t SZ_WHHF1 = (size_t)16 * 2 * 64 * 8 * 2;
constexpr size_t OFF_WIHR = OFF_WHHF + 3 * SZ_WHHF1;    // 2 x r-layout frags (Wih1, Wih2)
constexpr size_t SZ_WIHR1 = (size_t)16 * 2 * 64 * 8 * 2;
constexpr size_t OFF_BC   = OFF_WIHR + 2 * SZ_WIHR1;    // 3 x [256] f32
constexpr size_t OFF_PRE  = ((OFF_BC + 3 * 256 * 4 + 1023) / 1024) * 1024;  // [t][b][j][q] f32, layer 0 only
constexpr size_t SZ_PRE   = (size_t)T_ * B_ * G4 * 4;   // 33,554,432
constexpr size_t OFF_H2   = OFF_PRE + SZ_PRE;           // [B][T][HID] f16 (final layer h only)
constexpr size_t SZ_H     = (size_t)B_ * T_ * HID * 2;  // 4,194,304

__device__ __forceinline__ void async_copy16(const void* g, void* l) {
  __builtin_amdgcn_global_load_lds((const GLOBAL_AS void*)g, (LDS_AS void*)l, 16, 0, 0);
}

// within-row byte offset for pre[t][b][g] (plain, no swizzle): g=(q*64+j) -> j*16 + q*4
__device__ __forceinline__ int pre_col_byte(int g) {
  int j = g & 63, q = g >> 6;
  return (j << 4) | (q << 2);
}

__device__ __forceinline__ float fsig(float x) {
  return __builtin_amdgcn_rcpf(1.f + __builtin_amdgcn_exp2f(-1.4426950408889634f * x));
}
__device__ __forceinline__ float ftanh(float x) {
  return 1.f - 2.f * __builtin_amdgcn_rcpf(1.f + __builtin_amdgcn_exp2f(2.8853900817779268f * x));
}

// ================= pack kernel =================
__global__ void pack_kernel(const float* __restrict__ in0, const float* __restrict__ Wih0,
                            const float* __restrict__ Whh0, const float* __restrict__ bih0, const float* __restrict__ bhh0,
                            const float* __restrict__ Wih1, const float* __restrict__ Whh1, const float* __restrict__ bih1, const float* __restrict__ bhh1,
                            const float* __restrict__ Wih2, const float* __restrict__ Whh2, const float* __restrict__ bih2, const float* __restrict__ bhh2,
                            f16* __restrict__ xf, f16* __restrict__ wp0,
                            f16* __restrict__ whhf, f16* __restrict__ wihr, float* __restrict__ bc)
{
  const int stride = gridDim.x * blockDim.x;
  const int tid0 = blockIdx.x * blockDim.x + threadIdx.x;

  // xf: [B][T][FW], zero-pad f >= 65
  const int NX = B_ * T_ * FW;
  for (int i = tid0; i < NX; i += stride) {
    int f = i % FW; int bt = i / FW;
    float v = (f < IN_) ? in0[(size_t)bt * IN_ + f] : 0.f;
    xf[i] = (f16)v;
  }
  // wp0: [kc][nt][lane][8] ; k' = kc*32 + (l>>4)*8 + j ; g = nt*16 + (l&15)
  const int NW0 = KC0 * 16 * 64 * 8;
  for (int i = tid0; i < NW0; i += stride) {
    int j = i & 7, l = (i >> 3) & 63, nt = (i >> 9) & 15, kc = i >> 13;
    int kp = kc * 32 + ((l >> 4) * 8 + j);
    int g  = nt * 16 + (l & 15);
    int d = kp / FW, f = kp % FW;
    float v = (kp < 1800 && f < IN_) ? Wih0[(size_t)g * 1625 + d * IN_ + f] : 0.f;
    wp0[i] = (f16)v;
  }
  // whhf (r-layout): per layer, frag tt = wv*4+u, kf:
  //   g = u*64 + wv*16 + (l&15) ; k = kf*32 + (l>>4)*8 + e
  const float* whhs[3] = {Whh0, Whh1, Whh2};
  for (int i = tid0; i < 3 * 16384; i += stride) {
    int L = i >> 14, r = i & 16383;
    int e = r & 7, l = (r >> 3) & 63, kf = (r >> 9) & 1, tt = (r >> 10) & 15;
    int wv = tt >> 2, u = tt & 3;
    int g = u * 64 + wv * 16 + (l & 15);
    int k = kf * 32 + ((l >> 4) * 8) + e;
    whhf[i] = (f16)whhs[L][g * 64 + k];
  }
  // wihr (r-layout, same formula) from Wih1/Wih2 (both [256][64])
  const float* wihs[2] = {Wih1, Wih2};
  for (int i = tid0; i < 2 * 16384; i += stride) {
    int L = i >> 14, r = i & 16383;
    int e = r & 7, l = (r >> 3) & 63, kf = (r >> 9) & 1, tt = (r >> 10) & 15;
    int wv = tt >> 2, u = tt & 3;
    int g = u * 64 + wv * 16 + (l & 15);
    int k = kf * 32 + ((l >> 4) * 8) + e;
    wihr[i] = (f16)wihs[L][g * 64 + k];
  }
  // combined biases
  const float* bis[3] = {bih0, bih1, bih2};
  const float* bhs[3] = {bhh0, bhh1, bhh2};
  for (int i = tid0; i < 3 * 256; i += stride) {
    int L = i >> 8, g = i & 255;
    bc[i] = bis[L][g] + bhs[L][g];
  }
}

// ================= layer-0 windowed GEMM =================
// grid (32, 16): x = t-tile (64 rows), y = batch. 256 threads = 4 waves.
__global__ __launch_bounds__(256) void gemm0_kernel(const f16* __restrict__ xf, const f16* __restrict__ wp0,
                                                    const float* __restrict__ bc0, float* __restrict__ pre)
{
  __shared__ __align__(16) f16 frames[90 * FW];   // 12,960 B
  __shared__ __align__(16) f16 bbuf[16 * 64 * 8]; // 16,384 B
  const int tid = threadIdx.x, l = tid & 63, w = tid >> 6;
  const int b = blockIdx.y, t0 = blockIdx.x * 64;

  // zero frames (covers t-edge padding and the k'>=1800 tail rows)
  for (int c = tid; c < 810; c += 256) *(f32x4*)(&frames[c * 8]) = (f32x4)0.f;
  __syncthreads();

  // stage valid frame range [s0, s1) of this batch
  {
    const int st = t0 - 12;
    const int s0 = st < 0 ? 0 : st;
    const int s1 = (t0 + 78) < T_ ? (t0 + 78) : T_;
    const int dstrow = s0 - st;
    const int nchunk = (s1 - s0) * 9;  // 16B chunks (144 B/row)
    const f16* gsrc = xf + ((size_t)b * T_ + s0) * FW;
    for (int base = 0; base < 810; base += 256) {
      int idx = base + w * 64 + l;
      if (idx < nchunk) {
        char* ldsb = (char*)frames + dstrow * 144 + (base + w * 64) * 16;
        async_copy16((const char*)gsrc + (size_t)(base + w * 64) * 16 + l * 16, ldsb);
      }
    }
  }

  f32x4 acc[16];
#pragma unroll
  for (int i = 0; i < 16; ++i) acc[i] = (f32x4)0.f;

  for (int kc = 0; kc < KC0; ++kc) {
    __syncthreads();  // drains previous loads/reads; protects bbuf
    const f16* wsrc = wp0 + (size_t)kc * 8192;
#pragma unroll
    for (int i = 0; i < 4; ++i) {
      char* ldsb = (char*)bbuf + (i * 256 + w * 64) * 16;
      async_copy16((const char*)wsrc + (size_t)(i * 256 + w * 64 + l) * 16, ldsb);
    }
    __syncthreads();  // vmcnt(0) drain -> bbuf ready

    int kp0 = kc * 32 + ((l >> 4) * 8);
    int d = kp0 / FW, f = kp0 % FW;
    int r = w * 16 + (l & 15);
    half8 af = *(const half8*)(&frames[(r + d) * FW + f]);
#pragma unroll
    for (int nt = 0; nt < 16; ++nt) {
      half8 bf = *(const half8*)(&bbuf[(nt * 64 + l) * 8]);
      acc[nt] = __builtin_amdgcn_mfma_f32_16x16x32_f16(af, bf, acc[nt], 0, 0, 0);
    }
  }

  // epilogue: bias + plain [t][b][j][q] store
  const int n_ = l & 15, grp = l >> 4;
#pragma unroll
  for (int nt = 0; nt < 16; ++nt) {
    int g = nt * 16 + n_;
    float bias = bc0[g];
    int colByte = pre_col_byte(g);
#pragma unroll
    for (int rr = 0; rr < 4; ++rr) {
      int t = t0 + w * 16 + grp * 4 + rr;
      *(float*)((char*)pre + (size_t)t * 16384 + (size_t)b * 1024 + colByte) = acc[nt][rr] + bias;
    }
  }
}

// ================= fused 3-layer LSTM recurrence =================
// grid = 4 blocks x 768 threads (12 waves). Wave-group L = waves 4L..4L+3 runs
// layer L at time t_L = s - L. ONE barrier per step (parity analysis: within a
// step, all h-ring writes go to slot t&1 while all reads hit the other parity).
// Layer-0 pre streamed directly into a depth-3 REGISTER ring (no LDS, no vmcnt
// barrier); layers 1,2 fold Wih into 8 extra replicated-A MFMAs + bias.
__global__ __launch_bounds__(768) void r3_kernel(const float* __restrict__ pre,
                                                 const f16* __restrict__ whhf,
                                                 const f16* __restrict__ wihr,
                                                 const float* __restrict__ bc,
                                                 f16* __restrict__ h2out)
{
  __shared__ __align__(16) char hring[6 * 640];   // [layer][slot], 4 batches x 160 B
  const int tid = threadIdx.x, l = tid & 63, w = tid >> 6;
  const int L = w >> 2, wv = w & 3;
  const int n_ = l & 15, grp = l >> 4;
  const int b0 = blockIdx.x * 4;
  const int j = wv * 16 + n_;       // hidden index this lane updates
  const int bglob = b0 + grp;       // batch this lane updates
  const int arow = n_ >> 2;         // A-frag source batch (replicated rows)

  // recurrent (Whh) fragments, r-layout
  half8 bfh[4][2];
  const f16* wh = whhf + (size_t)L * 16384;
#pragma unroll
  for (int u = 0; u < 4; ++u)
#pragma unroll
    for (int kf = 0; kf < 2; ++kf)
      bfh[u][kf] = *(const half8*)(wh + (((wv * 4 + u) * 2 + kf) << 9) + (l << 3));

  // input (Wih) fragments for layers 1,2
  half8 bfx[4][2];
  if (L > 0) {
    const f16* wx = wihr + (size_t)(L - 1) * 16384;
#pragma unroll
    for (int u = 0; u < 4; ++u)
#pragma unroll
      for (int kf = 0; kf < 2; ++kf)
        bfx[u][kf] = *(const half8*)(wx + (((wv * 4 + u) * 2 + kf) << 9) + (l << 3));
  }

  float bi[4] = {0.f, 0.f, 0.f, 0.f};
  if (L > 0) {
#pragma unroll
    for (int u = 0; u < 4; ++u) bi[u] = bc[L * 256 + u * 64 + j];
  }

  // zero h rings (3840 B)
  for (int i = tid; i < 240; i += 768) *(f32x4*)(hring + i * 16) = (f32x4)0.f;
  float c = 0.f;

  // parity-selected LDS pointers (t&1 = sp ^ (L&1)); zero address math in-loop
  const int lp = L & 1;
  const int Lm1 = (L > 0) ? (L - 1) : 0;
  const char* ownRd0 = hring + (L * 2 + (1 ^ lp)) * 640 + arow * 160 + grp * 16;       // sp=0: slot (t-1)&1
  const char* ownRd1 = hring + (L * 2 + (0 ^ lp)) * 640 + arow * 160 + grp * 16;       // sp=1
  const char* inRd0  = hring + (Lm1 * 2 + (0 ^ lp)) * 640 + arow * 160 + grp * 16;     // sp=0: slot t&1
  const char* inRd1  = hring + (Lm1 * 2 + (1 ^ lp)) * 640 + arow * 160 + grp * 16;     // sp=1
  char* wr0 = hring + (L * 2 + (0 ^ lp)) * 640 + grp * 160 + j * 2;                    // sp=0: slot t&1
  char* wr1 = hring + (L * 2 + (1 ^ lp)) * 640 + grp * 160 + j * 2;                    // sp=1

  // register pre ring (group 0 only), depth 3; address-space(1) streaming ptr
  f32x4 P0 = (f32x4)0.f, P1 = (f32x4)0.f, P2 = (f32x4)0.f, P3 = (f32x4)0.f;
  const GLOBAL_AS char* preP =
      (const GLOBAL_AS char*)(uintptr_t)((const char*)pre + (size_t)bglob * 1024 + (size_t)j * 16);
  if (L == 0) {
    P0 = *(const GLOBAL_AS f32x4*)(preP);
    P1 = *(const GLOBAL_AS f32x4*)(preP + 16384);
    P2 = *(const GLOBAL_AS f32x4*)(preP + 32768);
    preP += 3 * 16384;
  }
  GLOBAL_AS f16* h2p = (GLOBAL_AS f16*)(uintptr_t)(h2out + (size_t)bglob * T_ * HID + j);

#define R3STEP(S_, PU_, PLD_, SP_)                                              \
  {                                                                             \
    asm volatile("s_waitcnt lgkmcnt(0)" ::: "memory");                          \
    __builtin_amdgcn_s_barrier();                                               \
    __builtin_amdgcn_sched_barrier(0);                                          \
    const int t = (S_) - L;                                                     \
    const bool act = (unsigned)t < (unsigned)T_;                                \
    if (L == 0 && (t + 3) < T_) {                                               \
      PLD_ = *(const GLOBAL_AS f32x4*)(preP);                                   \
      preP += 16384;                                                            \
    }                                                                           \
    if (act) {                                                                  \
      const char* Hc = (SP_) ? ownRd1 : ownRd0;                                 \
      half8 a0 = *(const half8*)(Hc);                                           \
      half8 a1 = *(const half8*)(Hc + 64);                                      \
      f32x4 acc[4];                                                             \
      _Pragma("unroll")                                                         \
      for (int u = 0; u < 4; ++u) {                                             \
        acc[u] = __builtin_amdgcn_mfma_f32_16x16x32_f16(a0, bfh[u][0], (f32x4)0.f, 0, 0, 0); \
        acc[u] = __builtin_amdgcn_mfma_f32_16x16x32_f16(a1, bfh[u][1], acc[u], 0, 0, 0);     \
      }                                                                         \
      if (L > 0) {                                                              \
        const char* Xc = (SP_) ? inRd1 : inRd0;                                 \
        half8 x0 = *(const half8*)(Xc);                                         \
        half8 x1 = *(const half8*)(Xc + 64);                                    \
        _Pragma("unroll")                                                       \
        for (int u = 0; u < 4; ++u) {                                           \
          acc[u] = __builtin_amdgcn_mfma_f32_16x16x32_f16(x0, bfx[u][0], acc[u], 0, 0, 0);   \
          acc[u] = __builtin_amdgcn_mfma_f32_16x16x32_f16(x1, bfx[u][1], acc[u], 0, 0, 0);   \
        }                                                                       \
      }                                                                         \
      float iv, fv, gv, ov;                                                     \
      if (L == 0) {                                                             \
        iv = acc[0][0] + PU_.x; fv = acc[1][0] + PU_.y;                         \
        gv = acc[2][0] + PU_.z; ov = acc[3][0] + PU_.w;                         \
      } else {                                                                  \
        iv = acc[0][0] + bi[0]; fv = acc[1][0] + bi[1];                         \
        gv = acc[2][0] + bi[2]; ov = acc[3][0] + bi[3];                         \
      }                                                                         \
      c = fsig(fv) * c + fsig(iv) * ftanh(gv);                                  \
      float hv = fsig(ov) * ftanh(c);                                           \
      f16 h16 = (f16)hv;                                                        \
      *(f16*)((SP_) ? wr1 : wr0) = h16;                                         \
      if (L == 2) { *h2p = h16; h2p += HID; }                                   \
    }                                                                           \
  }

  // steps s = 0 .. 2051 (covers t up to 2047 for L=2 at s=2049)
  for (int s4 = 0; s4 < T_ + 4; s4 += 4) {
    R3STEP(s4 + 0, P0, P3, 0)
    R3STEP(s4 + 1, P1, P0, 1)
    R3STEP(s4 + 2, P2, P1, 0)
    R3STEP(s4 + 3, P3, P2, 1)
  }
#undef R3STEP
}

// ================= final projection =================
__global__ __launch_bounds__(256) void fin_kernel(const f16* __restrict__ h2, const float* __restrict__ Wout,
                                                  const float* __restrict__ bout, float* __restrict__ out)
{
  __shared__ float wl[64];
  const int tid = threadIdx.x;
  if (tid < 64) wl[tid] = Wout[tid];
  __syncthreads();
  const int idx = blockIdx.x * 256 + tid;  // = b*T + t
  const f16* hr = h2 + (size_t)idx * HID;
  float acc = bout[0];
#pragma unroll
  for (int i = 0; i < 64; i += 8) {
    half8 hv = *(const half8*)(hr + i);
#pragma unroll
    for (int k = 0; k < 8; ++k) {
      float h = (float)hv[k];
      h = fmaxf(h, 0.f);
      acc += h * wl[i + k];
    }
  }
  out[idx] = fsig(acc);
}

// ================= launcher =================
extern "C" void kernel_launch(void* const* d_in, const int* in_sizes, int n_in,
                              void* d_out, int out_size, void* d_ws, size_t ws_size,
                              hipStream_t stream)
{
  (void)in_sizes; (void)n_in; (void)out_size; (void)ws_size;
  const float* in0  = (const float*)d_in[0];
  const float* Wih0 = (const float*)d_in[1];
  const float* Whh0 = (const float*)d_in[2];
  const float* bih0 = (const float*)d_in[3];
  const float* bhh0 = (const float*)d_in[4];
  const float* Wih1 = (const float*)d_in[5];
  const float* Whh1 = (const float*)d_in[6];
  const float* bih1 = (const float*)d_in[7];
  const float* bhh1 = (const float*)d_in[8];
  const float* Wih2 = (const float*)d_in[9];
  const float* Whh2 = (const float*)d_in[10];
  const float* bih2 = (const float*)d_in[11];
  const float* bhh2 = (const float*)d_in[12];
  const float* Wout = (const float*)d_in[13];
  const float* bout = (const float*)d_in[14];
  float* out = (float*)d_out;

  char* ws = (char*)d_ws;
  f16*   xf   = (f16*)(ws + OFF_XF);
  f16*   wp0  = (f16*)(ws + OFF_WP0);
  f16*   whhf = (f16*)(ws + OFF_WHHF);
  f16*   wihr = (f16*)(ws + OFF_WIHR);
  float* bc   = (float*)(ws + OFF_BC);
  float* pre  = (float*)(ws + OFF_PRE);
  f16*   h2   = (f16*)(ws + OFF_H2);

  pack_kernel<<<256, 256, 0, stream>>>(in0, Wih0, Whh0, bih0, bhh0,
                                       Wih1, Whh1, bih1, bhh1,
                                       Wih2, Whh2, bih2, bhh2,
                                       xf, wp0, whhf, wihr, bc);
  gemm0_kernel<<<dim3(32, 16), 256, 0, stream>>>(xf, wp0, bc, pre);
  r3_kernel<<<4, 768, 0, stream>>>(pre, whhf, wihr, bc, h2);
  fin_kernel<<<128, 256, 0, stream>>>(h2, Wout, bout, out);
}